// Round 6
// baseline (1056.291 us; speedup 1.0000x reference)
//
#include <hip/hip_runtime.h>
#include <cmath>

#define BS_TOK 32768      // B*S
#define DMODEL 512
#define NHEAD 8
#define DHEAD 64
#define NLAYER 3
#define FFDIM 2048
#define NCLS 6
#define BATCH 32
#define SEQ 1024
#define QKVW 1536         // 3*D

typedef short short8 __attribute__((ext_vector_type(8)));
typedef float float4v __attribute__((ext_vector_type(4)));
#define MFMA_BF16 __builtin_amdgcn_mfma_f32_16x16x32_bf16
#define QSCALE 0.18033688011112042f   // 0.125 * log2(e)

__device__ __forceinline__ unsigned short f2bf(float x) {
    return (unsigned short)((__float_as_uint(x) + 0x8000u) >> 16);  // round-half-away
}

// ---------------- embedding + sinusoidal PE -> X fp32 + Xb bf16 ----------------
__global__ __launch_bounds__(128) void embed_pe_kernel(const int* __restrict__ tokens,
                                                       const float* __restrict__ emb,
                                                       float* __restrict__ X,
                                                       unsigned short* __restrict__ Xb) {
    int t = blockIdx.x;
    int pos = t & (SEQ - 1);
    int tok = tokens[t];
    int d0 = threadIdx.x * 4;
    float4 e = *(const float4*)(emb + (size_t)tok * DMODEL + d0);
    const float c = -9.210340371976184f / 512.0f;
    float div0 = expf((float)d0 * c);
    float div1 = expf((float)(d0 + 2) * c);
    float a0 = (float)pos * div0;
    float a1 = (float)pos * div1;
    e.x += sinf(a0); e.y += cosf(a0);
    e.z += sinf(a1); e.w += cosf(a1);
    *(float4*)(X + (size_t)t * DMODEL + d0) = e;
    *(ushort4*)(Xb + (size_t)t * DMODEL + d0) =
        make_ushort4(f2bf(e.x), f2bf(e.y), f2bf(e.z), f2bf(e.w));
}

// ---------------- generic transpose+convert (fc_w): f32 [R][C] -> bf16 [C][R] ----------------
__global__ __launch_bounds__(256) void transcvt_kernel(const float* __restrict__ in,
                                                       unsigned short* __restrict__ out,
                                                       int R, int C) {
    __shared__ float t[32][33];
    size_t base = (size_t)blockIdx.z * R * C;
    int c0 = blockIdx.x * 32, r0 = blockIdx.y * 32;
    int tx = threadIdx.x & 31, ty = threadIdx.x >> 5;
#pragma unroll
    for (int i = 0; i < 4; i++)
        t[ty + i * 8][tx] = in[base + (size_t)(r0 + ty + i * 8) * C + c0 + tx];
    __syncthreads();
#pragma unroll
    for (int i = 0; i < 4; i++)
        out[base + (size_t)(c0 + ty + i * 8) * R + r0 + tx] = f2bf(t[tx][ty + i * 8]);
}

// ---------------- qkv_w transpose+convert with head-permute + Q prescale ----------------
__global__ __launch_bounds__(256) void transcvt_qkv_kernel(const float* __restrict__ in,
                                                           unsigned short* __restrict__ out) {
    __shared__ float t[32][33];
    int l = blockIdx.z;
    int n0 = blockIdx.x * 32, r0 = blockIdx.y * 32;
    int seg = n0 >> 9, nn = n0 & 511, h = nn >> 6, d0 = nn & 63;
    int c0 = h * 192 + seg * 64 + d0;
    float s = (seg == 0) ? QSCALE : 1.f;
    const float* inp = in + (size_t)l * DMODEL * QKVW;
    unsigned short* op = out + (size_t)l * QKVW * DMODEL;
    int tx = threadIdx.x & 31, ty = threadIdx.x >> 5;
#pragma unroll
    for (int i = 0; i < 4; i++)
        t[ty + i * 8][tx] = inp[(size_t)(r0 + ty + i * 8) * QKVW + c0 + tx];
    __syncthreads();
#pragma unroll
    for (int i = 0; i < 4; i++)
        op[(size_t)(n0 + ty + i * 8) * DMODEL + r0 + tx] = f2bf(t[tx][ty + i * 8] * s);
}

// ---------------- permuted (+scaled) qkv bias ----------------
__global__ __launch_bounds__(256) void permbias_kernel(const float* __restrict__ qkv_b,
                                                       float* __restrict__ pb) {
    int i = blockIdx.x * 256 + threadIdx.x;   // < L*1536
    int l = i / QKVW, n = i - l * QKVW;
    int seg = n >> 9, nn = n & 511, h = nn >> 6, d = nn & 63;
    float s = (seg == 0) ? QSCALE : 1.f;
    pb[i] = qkv_b[l * QKVW + h * 192 + seg * 64 + d] * s;
}

// ---------------- QKV GEMM: [M,1536]perm = Xb[M,512] @ Wt^T + pb ----------------
__global__ __launch_bounds__(256) void gemm_qkv_kernel(const unsigned short* __restrict__ A,
                                                       const unsigned short* __restrict__ Bt,
                                                       const float* __restrict__ pb,
                                                       unsigned short* __restrict__ QKc,
                                                       unsigned short* __restrict__ Vt,
                                                       int M) {
    __shared__ unsigned short As[128 * 40];
    __shared__ unsigned short Bs[128 * 40];
    int bm = blockIdx.y * 128, bn = blockIdx.x * 128;
    int tid = threadIdx.x;
    int w = tid >> 6, lane = tid & 63, l15 = lane & 15, quad = lane >> 4;
    int wm = (w & 1) * 64, wn = (w >> 1) * 64;

    float4v acc[4][4];
    float4v z = {0.f, 0.f, 0.f, 0.f};
#pragma unroll
    for (int i = 0; i < 4; i++)
#pragma unroll
        for (int j = 0; j < 4; j++) acc[i][j] = z;

    int r0 = tid >> 2, o0 = (tid & 3) * 8;
    int r1 = (tid + 256) >> 2, o1 = (tid & 3) * 8;

    for (int k0 = 0; k0 < DMODEL; k0 += 32) {
        __syncthreads();
        *(short8*)&As[r0 * 40 + o0] = *(const short8*)(A + (size_t)(bm + r0) * DMODEL + k0 + o0);
        *(short8*)&As[r1 * 40 + o1] = *(const short8*)(A + (size_t)(bm + r1) * DMODEL + k0 + o1);
        *(short8*)&Bs[r0 * 40 + o0] = *(const short8*)(Bt + (size_t)(bn + r0) * DMODEL + k0 + o0);
        *(short8*)&Bs[r1 * 40 + o1] = *(const short8*)(Bt + (size_t)(bn + r1) * DMODEL + k0 + o1);
        __syncthreads();
        short8 af[4], bf[4];
#pragma unroll
        for (int i = 0; i < 4; i++)
            af[i] = *(short8*)&As[(wm + i * 16 + l15) * 40 + quad * 8];
#pragma unroll
        for (int j = 0; j < 4; j++)
            bf[j] = *(short8*)&Bs[(wn + j * 16 + l15) * 40 + quad * 8];
#pragma unroll
        for (int i = 0; i < 4; i++)
#pragma unroll
            for (int j = 0; j < 4; j++)
                acc[i][j] = MFMA_BF16(af[i], bf[j], acc[i][j], 0, 0, 0);
    }

    float bj[4];
#pragma unroll
    for (int j = 0; j < 4; j++) bj[j] = pb[bn + wn + j * 16 + l15];

    if (bn < 1024) {          // Q | K -> row-major QKc[tok][1024]
#pragma unroll
        for (int i = 0; i < 4; i++)
#pragma unroll
            for (int r = 0; r < 4; r++) {
                size_t row = (size_t)(bm + wm + i * 16 + quad * 4 + r);
#pragma unroll
                for (int j = 0; j < 4; j++)
                    QKc[row * 1024 + bn + wn + j * 16 + l15] = f2bf(acc[i][j][r] + bj[j]);
            }
    } else {                  // V -> transposed Vt[bh][d][s]
        int bl = bm >> 10;
        int sbase = (bm & 1023) + wm;
#pragma unroll
        for (int j = 0; j < 4; j++) {
            int colp = bn - 1024 + wn + j * 16 + l15;
            int h = colp >> 6, d = colp & 63;
            unsigned short* vb = Vt + ((size_t)(bl * 8 + h) * 64 + d) * 1024 + sbase;
#pragma unroll
            for (int i = 0; i < 4; i++) {
                ushort4 v4 = make_ushort4(f2bf(acc[i][j][0] + bj[j]),
                                          f2bf(acc[i][j][1] + bj[j]),
                                          f2bf(acc[i][j][2] + bj[j]),
                                          f2bf(acc[i][j][3] + bj[j]));
                *(ushort4*)(vb + i * 16 + quad * 4) = v4;
            }
        }
    }
}

// ---------------- bf16 MFMA flash attention v2: S^T orientation, Q-block 256 ----------------
// S^T = MFMA(A=K, B=Q): C col = q (lane&15), row = key (quad*4+r)  => P writes are b64,
// PV = MFMA(A=V^T, B=P): accumulates O^T (col = q, row = d).
// Grid: (bh, q0/256) so all q-blocks of one bh share an XCD (L2 locality).
__global__ __launch_bounds__(256, 2) void attn_kernel(const unsigned short* __restrict__ QKc,
                                                      const unsigned short* __restrict__ Vt,
                                                      unsigned short* __restrict__ O) {
    __shared__ unsigned short Ks[64 * 72];        // K[key][d]
    __shared__ unsigned short Vts[64 * 72];       // V^T[d][key]
    __shared__ unsigned short Ps[4 * 64 * 72];    // per-wave P[q][key]
    int bh = blockIdx.x;
    int b = bh >> 3, h = bh & 7;
    int q0 = blockIdx.y * 256;
    int tid = threadIdx.x;
    int w = tid >> 6, lane = tid & 63, l15 = lane & 15, quad = lane >> 4;
    unsigned short* Psb = &Ps[w * 64 * 72];
    const unsigned short* Kg = QKc + (size_t)b * SEQ * 1024 + 512 + h * 64;
    const unsigned short* Vg = Vt + (size_t)bh * 64 * 1024;

    // Q fragments: wave owns 64 q rows (4 n-tiles); B-layout [n=q=l15][k=d=quad*8+j]
    short8 qf[4][2];
#pragma unroll
    for (int nt = 0; nt < 4; nt++) {
        const unsigned short* qb =
            QKc + (size_t)(b * SEQ + q0 + w * 64 + nt * 16 + l15) * 1024 + h * 64;
        qf[nt][0] = *(const short8*)(qb + quad * 8);
        qf[nt][1] = *(const short8*)(qb + 32 + quad * 8);
    }

    float lsum[4] = {0.f, 0.f, 0.f, 0.f};
    float4v accO[4][4];   // [dt][nt], O^T: col=q, rows=d
    float4v z = {0.f, 0.f, 0.f, 0.f};
#pragma unroll
    for (int dt = 0; dt < 4; dt++)
#pragma unroll
        for (int nt = 0; nt < 4; nt++) accO[dt][nt] = z;

    for (int jt = 0; jt < SEQ / 64; jt++) {
        __syncthreads();
#pragma unroll
        for (int cc = 0; cc < 2; cc++) {
            int c = tid + cc * 256;
            int r = c >> 3, o = (c & 7) * 8;
            *(short8*)&Ks[r * 72 + o] = *(const short8*)(Kg + (size_t)(jt * 64 + r) * 1024 + o);
            *(short8*)&Vts[r * 72 + o] = *(const short8*)(Vg + (size_t)r * 1024 + jt * 64 + o);
        }
        __syncthreads();

        // S^T + exp2 + b64 P write
#pragma unroll
        for (int mt = 0; mt < 4; mt++) {
            short8 kf0 = *(short8*)&Ks[(mt * 16 + l15) * 72 + quad * 8];
            short8 kf1 = *(short8*)&Ks[(mt * 16 + l15) * 72 + 32 + quad * 8];
#pragma unroll
            for (int nt = 0; nt < 4; nt++) {
                float4v sv = MFMA_BF16(kf0, qf[nt][0], z, 0, 0, 0);
                sv = MFMA_BF16(kf1, qf[nt][1], sv, 0, 0, 0);
                float p0 = exp2f(sv[0]), p1 = exp2f(sv[1]);
                float p2 = exp2f(sv[2]), p3 = exp2f(sv[3]);
                lsum[nt] += (p0 + p1) + (p2 + p3);
                unsigned int u0 = (unsigned int)f2bf(p0) | ((unsigned int)f2bf(p1) << 16);
                unsigned int u1 = (unsigned int)f2bf(p2) | ((unsigned int)f2bf(p3) << 16);
                *(uint2*)&Psb[(nt * 16 + l15) * 72 + mt * 16 + quad * 4] = make_uint2(u0, u1);
            }
        }

        // PV: O^T += V^T · P^T  (wave-private P, in-order DS => no barrier)
#pragma unroll
        for (int kc = 0; kc < 2; kc++) {
            short8 vf[4];
#pragma unroll
            for (int dt = 0; dt < 4; dt++)
                vf[dt] = *(short8*)&Vts[(dt * 16 + l15) * 72 + kc * 32 + quad * 8];
#pragma unroll
            for (int nt = 0; nt < 4; nt++) {
                short8 pfr = *(short8*)&Psb[(nt * 16 + l15) * 72 + kc * 32 + quad * 8];
#pragma unroll
                for (int dt = 0; dt < 4; dt++)
                    accO[dt][nt] = MFMA_BF16(vf[dt], pfr, accO[dt][nt], 0, 0, 0);
            }
        }
    }

    // epilogue: reduce lsum across quads (key-partials), normalize, b64 stores
#pragma unroll
    for (int nt = 0; nt < 4; nt++) {
        float s = lsum[nt];
        s += __shfl_xor(s, 16);
        s += __shfl_xor(s, 32);
        float rinv = 1.f / s;
        size_t row = (size_t)(b * SEQ + q0 + w * 64 + nt * 16 + l15);
#pragma unroll
        for (int dt = 0; dt < 4; dt++) {
            ushort4 o4 = make_ushort4(f2bf(accO[dt][nt][0] * rinv),
                                      f2bf(accO[dt][nt][1] * rinv),
                                      f2bf(accO[dt][nt][2] * rinv),
                                      f2bf(accO[dt][nt][3] * rinv));
            *(ushort4*)(O + row * DMODEL + h * DHEAD + dt * 16 + quad * 4) = o4;
        }
    }
}

// ---------------- fused out-proj + bias + residual + LayerNorm ----------------
__global__ __launch_bounds__(256) void proj_ln_kernel(const unsigned short* __restrict__ A,
                                                      const unsigned short* __restrict__ Bt,
                                                      const float* __restrict__ bias,
                                                      const float* __restrict__ gamma,
                                                      const float* __restrict__ beta,
                                                      float* __restrict__ X,
                                                      unsigned short* __restrict__ Xb) {
    __shared__ unsigned short As[32 * 40];
    __shared__ unsigned short Bs[512 * 40];
    __shared__ float redS[4][32], redQ[4][32];
    int bm = blockIdx.x * 32;
    int tid = threadIdx.x;
    int w = tid >> 6, lane = tid & 63, l15 = lane & 15, quad = lane >> 4;
    int wn = w * 128;

    float4v acc[2][8];
    float4v z = {0.f, 0.f, 0.f, 0.f};
#pragma unroll
    for (int i = 0; i < 2; i++)
#pragma unroll
        for (int j = 0; j < 8; j++) acc[i][j] = z;

    for (int k0 = 0; k0 < DMODEL; k0 += 32) {
        __syncthreads();
        if (tid < 128) {
            int r = tid >> 2, o = (tid & 3) * 8;
            *(short8*)&As[r * 40 + o] = *(const short8*)(A + (size_t)(bm + r) * DMODEL + k0 + o);
        }
#pragma unroll
        for (int u = 0; u < 8; u++) {
            int c = tid + u * 256;
            int r = c >> 2, o = (c & 3) * 8;
            *(short8*)&Bs[r * 40 + o] = *(const short8*)(Bt + (size_t)r * DMODEL + k0 + o);
        }
        __syncthreads();
        short8 af[2];
#pragma unroll
        for (int i = 0; i < 2; i++)
            af[i] = *(short8*)&As[(i * 16 + l15) * 40 + quad * 8];
#pragma unroll
        for (int j = 0; j < 8; j++) {
            short8 bf = *(short8*)&Bs[(wn + j * 16 + l15) * 40 + quad * 8];
            acc[0][j] = MFMA_BF16(af[0], bf, acc[0][j], 0, 0, 0);
            acc[1][j] = MFMA_BF16(af[1], bf, acc[1][j], 0, 0, 0);
        }
    }

    float bj[8], g[8], be[8];
#pragma unroll
    for (int j = 0; j < 8; j++) {
        int col = wn + j * 16 + l15;
        bj[j] = bias[col]; g[j] = gamma[col]; be[j] = beta[col];
    }

    float o[2][4][8];
#pragma unroll
    for (int i = 0; i < 2; i++)
#pragma unroll
        for (int r = 0; r < 4; r++) {
            int lrow = i * 16 + quad * 4 + r;
            size_t row = (size_t)(bm + lrow);
            float ss = 0.f, qq = 0.f;
#pragma unroll
            for (int j = 0; j < 8; j++) {
                float v = acc[i][j][r] + bj[j] + X[row * DMODEL + wn + j * 16 + l15];
                o[i][r][j] = v; ss += v; qq += v * v;
            }
#pragma unroll
            for (int mask = 1; mask < 16; mask <<= 1) {
                ss += __shfl_xor(ss, mask);
                qq += __shfl_xor(qq, mask);
            }
            if (l15 == 0) { redS[w][lrow] = ss; redQ[w][lrow] = qq; }
        }
    __syncthreads();
#pragma unroll
    for (int i = 0; i < 2; i++)
#pragma unroll
        for (int r = 0; r < 4; r++) {
            int lrow = i * 16 + quad * 4 + r;
            float S = redS[0][lrow] + redS[1][lrow] + redS[2][lrow] + redS[3][lrow];
            float Q = redQ[0][lrow] + redQ[1][lrow] + redQ[2][lrow] + redQ[3][lrow];
            float mean = S * (1.f / 512.f);
            float var = Q * (1.f / 512.f) - mean * mean;
            float rstd = rsqrtf(var + 1e-5f);
            size_t row = (size_t)(bm + lrow);
#pragma unroll
            for (int j = 0; j < 8; j++) {
                float n = (o[i][r][j] - mean) * rstd * g[j] + be[j];
                X[row * DMODEL + wn + j * 16 + l15] = n;
                Xb[row * DMODEL + wn + j * 16 + l15] = f2bf(n);
            }
        }
}

// ---------------- pooled zero + two-stage mean pool ----------------
__global__ __launch_bounds__(256) void zero_kernel(float* __restrict__ p) {
    p[blockIdx.x * 256 + threadIdx.x] = 0.f;
}
__global__ __launch_bounds__(128) void pool_kernel(const float* __restrict__ X,
                                                   float* __restrict__ pooled) {
    int b = blockIdx.x, ch = blockIdx.y;
    int d0 = threadIdx.x * 4;
    float4 acc = make_float4(0.f, 0.f, 0.f, 0.f);
    const float* base = X + (size_t)(b * SEQ + ch * 64) * DMODEL + d0;
    for (int s2 = 0; s2 < 64; s2++) {
        float4 v = *(const float4*)(base + (size_t)s2 * DMODEL);
        acc.x += v.x; acc.y += v.y; acc.z += v.z; acc.w += v.w;
    }
    atomicAdd(pooled + b * DMODEL + d0 + 0, acc.x);
    atomicAdd(pooled + b * DMODEL + d0 + 1, acc.y);
    atomicAdd(pooled + b * DMODEL + d0 + 2, acc.z);
    atomicAdd(pooled + b * DMODEL + d0 + 3, acc.w);
}

// ---------------- MLP head ----------------
__global__ __launch_bounds__(256) void fc1_kernel(const float* __restrict__ pooled,
                                                  const float* __restrict__ fc1_w,
                                                  const float* __restrict__ fc1_b,
                                                  float* __restrict__ h) {
    __shared__ float p[DMODEL];
    int ffc = blockIdx.x, b = blockIdx.y;
    int tid = threadIdx.x;
    p[tid] = pooled[b * DMODEL + tid] * (1.f / 1024.f);
    p[tid + 256] = pooled[b * DMODEL + tid + 256] * (1.f / 1024.f);
    __syncthreads();
    int ff = ffc * 256 + tid;
    float acc = fc1_b[ff];
    for (int k = 0; k < DMODEL; k++) acc += p[k] * fc1_w[(size_t)k * FFDIM + ff];
    h[(size_t)b * FFDIM + ff] = fmaxf(acc, 0.f);
}

__global__ __launch_bounds__(256) void fc2_kernel(const float* __restrict__ h,
                                                  const float* __restrict__ fc2_w,
                                                  const float* __restrict__ fc2_b,
                                                  float* __restrict__ out) {
    __shared__ float red[NCLS][256];
    int b = blockIdx.x, tid = threadIdx.x;
    float a[NCLS];
#pragma unroll
    for (int c = 0; c < NCLS; c++) a[c] = 0.f;
    int k0 = tid * 8;
#pragma unroll
    for (int u = 0; u < 8; u++) {
        float hv = h[(size_t)b * FFDIM + k0 + u];
#pragma unroll
        for (int c = 0; c < NCLS; c++) a[c] += hv * fc2_w[(k0 + u) * NCLS + c];
    }
#pragma unroll
    for (int c = 0; c < NCLS; c++) red[c][tid] = a[c];
    __syncthreads();
    if (tid < NCLS) {
        float s = 0.f;
        for (int i = 0; i < 256; i++) s += red[tid][i];
        out[b * NCLS + tid] = s + fc2_b[tid];
    }
}

extern "C" void kernel_launch(void* const* d_in, const int* in_sizes, int n_in,
                              void* d_out, int out_size, void* d_ws, size_t ws_size,
                              hipStream_t stream) {
    const int* tokens = (const int*)d_in[0];
    const float* emb = (const float*)d_in[1];
    const float* qkv_w = (const float*)d_in[2];
    const float* qkv_b = (const float*)d_in[3];
    const float* fc_w = (const float*)d_in[4];
    const float* fc_b = (const float*)d_in[5];
    const float* gamma = (const float*)d_in[6];
    const float* beta = (const float*)d_in[7];
    const float* fc1_w = (const float*)d_in[8];
    const float* fc1_b = (const float*)d_in[9];
    const float* fc2_w = (const float*)d_in[10];
    const float* fc2_b = (const float*)d_in[11];
    float* out = (float*)d_out;

    char* p = (char*)d_ws;
    float* X = (float*)p;                         p += (size_t)BS_TOK * DMODEL * 4;  // 64 MB
    unsigned short* Xb = (unsigned short*)p;      p += (size_t)BS_TOK * DMODEL * 2;  // 32 MB
    float* pooled = (float*)p;                    p += (size_t)BATCH * DMODEL * 4;
    float* hbuf = (float*)p;                      p += (size_t)BATCH * FFDIM * 4;
    float* pb = (float*)p;                        p += (size_t)NLAYER * QKVW * 4;
    unsigned short* qkv_wbt = (unsigned short*)p; p += (size_t)NLAYER * QKVW * DMODEL * 2;
    unsigned short* fc_wt = (unsigned short*)p;   p += (size_t)NLAYER * DMODEL * DMODEL * 2;
    size_t fixed_bytes = (size_t)(p - (char*)d_ws);
    size_t per_batch = (size_t)SEQ * 1024 * 2 + (size_t)NHEAD * 64 * SEQ * 2
                     + (size_t)SEQ * DMODEL * 2;
    int chunkB = 1;
    for (int cb = 32; cb >= 1; cb >>= 1)
        if (fixed_bytes + (size_t)cb * per_batch <= ws_size) { chunkB = cb; break; }
    unsigned short* QKc = (unsigned short*)p;     p += (size_t)chunkB * SEQ * 1024 * 2;
    unsigned short* Vt = (unsigned short*)p;      p += (size_t)chunkB * NHEAD * 64 * SEQ * 2;
    unsigned short* Oc = (unsigned short*)p;
    int rows = chunkB * SEQ;
    int nchunks = BATCH / chunkB;

    embed_pe_kernel<<<BS_TOK, 128, 0, stream>>>(tokens, emb, X, Xb);
    permbias_kernel<<<NLAYER * QKVW / 256, 256, 0, stream>>>(qkv_b, pb);
    transcvt_qkv_kernel<<<dim3(QKVW / 32, DMODEL / 32, NLAYER), 256, 0, stream>>>(
        qkv_w, qkv_wbt);
    transcvt_kernel<<<dim3(DMODEL / 32, DMODEL / 32, NLAYER), 256, 0, stream>>>(
        fc_w, fc_wt, DMODEL, DMODEL);

    for (int l = 0; l < NLAYER; l++) {
        for (int c = 0; c < nchunks; c++) {
            unsigned short* Xbc = Xb + (size_t)c * rows * DMODEL;
            float* Xc = X + (size_t)c * rows * DMODEL;
            gemm_qkv_kernel<<<dim3(QKVW / 128, rows / 128), 256, 0, stream>>>(
                Xbc, qkv_wbt + (size_t)l * QKVW * DMODEL, pb + (size_t)l * QKVW,
                QKc, Vt, rows);
            attn_kernel<<<dim3(chunkB * NHEAD, SEQ / 256), 256, 0, stream>>>(QKc, Vt, Oc);
            proj_ln_kernel<<<rows / 32, 256, 0, stream>>>(
                Oc, fc_wt + (size_t)l * DMODEL * DMODEL, fc_b + (size_t)l * DMODEL,
                gamma, beta, Xc, Xbc);
        }
    }

    zero_kernel<<<BATCH * DMODEL / 256, 256, 0, stream>>>(pooled);
    pool_kernel<<<dim3(BATCH, 16), 128, 0, stream>>>(X, pooled);
    fc1_kernel<<<dim3(FFDIM / 256, BATCH), 256, 0, stream>>>(pooled, fc1_w, fc1_b, hbuf);
    fc2_kernel<<<BATCH, 256, 0, stream>>>(hbuf, fc2_w, fc2_b, out);
}